// Round 16
// baseline (134.239 us; speedup 1.0000x reference)
//
#include <hip/hip_runtime.h>
#include <stdint.h>

typedef uint32_t u32;
typedef __attribute__((ext_vector_type(4))) float f32x4;
typedef __attribute__((ext_vector_type(8))) short short8;

#define NBATCH 16
#define NPIX   16384      // H*W
#define NPB    1048576    // per-batch flat elems (C*H*W = 1024*1024)

__device__ __forceinline__ ushort f2bf(float f) {
  u32 b = __builtin_bit_cast(u32, f);
  return (ushort)((b + 0x7FFFu + ((b >> 16) & 1u)) >> 16);
}
__device__ __forceinline__ float bf2f(ushort h) {
  return __builtin_bit_cast(float, (u32)h << 16);
}

// async global->LDS, 16B per lane. LDS dest must be wave-uniform base;
// HW scatters lane i at base + i*16. Global source is per-lane.
__device__ __forceinline__ void gload16(const void* g, void* l) {
  __builtin_amdgcn_global_load_lds(
      (const __attribute__((address_space(1))) u32*)g,
      (__attribute__((address_space(3))) u32*)l,
      16, 0, 0);
}

// ---------------- Kernel 0: pack weights for MFMA-proj -----------------------
// Wpk[96][128] bf16: rows 0..15 = q,k: cols[0:64]=Wh (round), [64:128]=Wl
// (W - Wh, exact split). Rows 16..79 = v: cols[0:64]=bf16(Wv), rest 0.
__global__ void prep_w2(const float* __restrict__ Wq, const float* __restrict__ bq,
                        const float* __restrict__ Wk, const float* __restrict__ bk,
                        const float* __restrict__ Wv, const float* __restrict__ bv,
                        ushort* __restrict__ Wpk, float* __restrict__ bpk)
{
  int gid = blockIdx.x * 256 + threadIdx.x;
  if (gid < 12288) {
    int m = gid >> 7, kk = gid & 127;
    int ch = kk & 63;
    ushort outv = 0;
    if (m < 8) {
      float wv = Wq[m * 64 + ch];
      ushort h = f2bf(wv);
      outv = (kk < 64) ? h : f2bf(wv - bf2f(h));
    } else if (m < 16) {
      float wv = Wk[(m - 8) * 64 + ch];
      ushort h = f2bf(wv);
      outv = (kk < 64) ? h : f2bf(wv - bf2f(h));
    } else if (m < 80) {
      outv = (kk < 64) ? f2bf(Wv[(m - 16) * 64 + ch]) : (ushort)0;
    }
    Wpk[gid] = outv;
  } else if (gid < 12368) {
    int o = gid - 12288;
    bpk[o] = (o < 8) ? bq[o] : (o < 16 ? bk[o - 8] : bv[o - 16]);
  }
}

// ---------------- Kernel 1: MFMA proj + fused transposes, 16-l chunk ---------
// R15 proj10 structure with l-chunk 8->16: each (ch,tc) strip is now a 64B
// contiguous run (vs 32B) -> HBM-efficient staging; 1024 blocks x 512 thr
// (8 waves), xs[64][256] fp32 = 64KB -> 2 blocks/CU (16 waves). Wave w
// computes ALL 5 M-tiles for its 2 N-tiles (px = (w*2+i)*16 + l15).
// Epilogue = proj8's verified l-chunk-16 epilogue (strides 260/264).
__global__ __launch_bounds__(512) void proj11(
    const float* __restrict__ x, const ushort* __restrict__ Wpk,
    const float* __restrict__ bpk,
    ushort* __restrict__ Qt2, ushort* __restrict__ Kt2,
    ushort* __restrict__ Vt)
{
  __shared__ __align__(16) char smem[65536];
  float* xs = (float*)smem;                       // [64][256]
  int t = threadIdx.x;
  int w = t >> 6, lane = t & 63;
  int l15 = lane & 15, l4 = lane >> 4;

  // XCD-chunk remap: 1024 blocks, 128 per XCD = 2 batches, consecutive l0.
  int g = blockIdx.x;
  int lin = (g & 7) * 128 + (g >> 3);
  int b = lin >> 6;
  int l0 = (lin & 63) << 4;
  const float* xb = x + (size_t)b * NPB + l0;

  // stage: slot f (16B) = x[ch][tc*1024 + qq*4 ..+4), f = ch*64 + tc*4 + qq
  // -> xs[ch][px], px = tc*16 + qq*4 + e  (64B contiguous per (ch,tc))
  #pragma unroll
  for (int it = 0; it < 8; ++it) {
    int f0 = it * 512 + w * 64;
    int f = f0 + lane;
    int ch = f >> 6, r2 = f & 63, tc = r2 >> 2, qq = r2 & 3;
    gload16(xb + (size_t)ch * NPIX + tc * 1024 + qq * 4, xs + (size_t)f0 * 4);
  }

  // A-frags: frag(mt,kc)[lane] = Wpk[mt*16 + l15][kc*32 + l4*8 ..+8]
  const uint4* Wp4 = (const uint4*)Wpk;   // row stride 16 uint4
  uint4 Afrag[12];
  #pragma unroll
  for (int kc = 0; kc < 4; ++kc)
    Afrag[kc] = Wp4[l15 * 16 + kc * 4 + l4];
  #pragma unroll
  for (int mt = 1; mt < 5; ++mt)
    #pragma unroll
    for (int kc = 0; kc < 2; ++kc)
      Afrag[2 + mt * 2 + kc] = Wp4[(mt * 16 + l15) * 16 + kc * 4 + l4];

  // acc init = bias (C row m = mt*16 + l4*4 + r)
  f32x4 acc[5][2];
  #pragma unroll
  for (int mt = 0; mt < 5; ++mt) {
    f32x4 bv4;
    #pragma unroll
    for (int r = 0; r < 4; ++r) bv4[r] = bpk[mt * 16 + l4 * 4 + r];
    acc[mt][0] = bv4; acc[mt][1] = bv4;
  }

  __syncthreads();   // drains gloads + A-frag loads

  #pragma unroll
  for (int i = 0; i < 2; ++i) {
    int px = (w * 2 + i) * 16 + l15;
    u32 xr[16];
    #pragma unroll
    for (int kc = 0; kc < 2; ++kc)
      #pragma unroll
      for (int j = 0; j < 8; ++j)
        xr[kc * 8 + j] = ((const u32*)xs)[(kc * 32 + l4 * 8 + j) * 256 + px];
    uint4 bxh[2], bxl[2];
    #pragma unroll
    for (int kc = 0; kc < 2; ++kc)
      #pragma unroll
      for (int p = 0; p < 4; ++p) {
        u32 a = xr[kc * 8 + 2 * p], c = xr[kc * 8 + 2 * p + 1];
        ((u32*)&bxh[kc])[p] = (a >> 16) | (c & 0xFFFF0000u);
        float fa = __builtin_bit_cast(float, a) -
                   __builtin_bit_cast(float, a & 0xFFFF0000u);
        float fc = __builtin_bit_cast(float, c) -
                   __builtin_bit_cast(float, c & 0xFFFF0000u);
        u32 la = __builtin_bit_cast(u32, fa), lc = __builtin_bit_cast(u32, fc);
        ((u32*)&bxl[kc])[p] = (la >> 16) | (lc & 0xFFFF0000u);
      }
    short8 h0 = __builtin_bit_cast(short8, bxh[0]);
    short8 h1 = __builtin_bit_cast(short8, bxh[1]);
    short8 s0 = __builtin_bit_cast(short8, bxl[0]);
    short8 s1 = __builtin_bit_cast(short8, bxl[1]);
    acc[0][i] = __builtin_amdgcn_mfma_f32_16x16x32_bf16(
        __builtin_bit_cast(short8, Afrag[0]), h0, acc[0][i], 0, 0, 0);
    acc[0][i] = __builtin_amdgcn_mfma_f32_16x16x32_bf16(
        __builtin_bit_cast(short8, Afrag[1]), h1, acc[0][i], 0, 0, 0);
    acc[0][i] = __builtin_amdgcn_mfma_f32_16x16x32_bf16(
        __builtin_bit_cast(short8, Afrag[0]), s0, acc[0][i], 0, 0, 0);
    acc[0][i] = __builtin_amdgcn_mfma_f32_16x16x32_bf16(
        __builtin_bit_cast(short8, Afrag[1]), s1, acc[0][i], 0, 0, 0);
    acc[0][i] = __builtin_amdgcn_mfma_f32_16x16x32_bf16(
        __builtin_bit_cast(short8, Afrag[2]), h0, acc[0][i], 0, 0, 0);
    acc[0][i] = __builtin_amdgcn_mfma_f32_16x16x32_bf16(
        __builtin_bit_cast(short8, Afrag[3]), h1, acc[0][i], 0, 0, 0);
    #pragma unroll
    for (int mt = 1; mt < 5; ++mt) {
      acc[mt][i] = __builtin_amdgcn_mfma_f32_16x16x32_bf16(
          __builtin_bit_cast(short8, Afrag[2 + mt * 2]), h0, acc[mt][i], 0, 0, 0);
      acc[mt][i] = __builtin_amdgcn_mfma_f32_16x16x32_bf16(
          __builtin_bit_cast(short8, Afrag[3 + mt * 2]), h1, acc[mt][i], 0, 0, 0);
    }
  }
  __syncthreads();   // all xs reads done before epilogue overwrites smem

  float*  qkl = (float*)smem;                    // [16][260]
  ushort* vl  = (ushort*)(smem + 16 * 260 * 4);  // [64][264]  (total 50.4KB)
  #pragma unroll
  for (int i = 0; i < 2; ++i) {
    int px = (w * 2 + i) * 16 + l15;
    #pragma unroll
    for (int r = 0; r < 4; ++r)
      qkl[(l4 * 4 + r) * 260 + px] = acc[0][i][r];
    #pragma unroll
    for (int mt = 1; mt < 5; ++mt)
      #pragma unroll
      for (int r = 0; r < 4; ++r)
        vl[((mt - 1) * 16 + l4 * 4 + r) * 264 + px] = f2bf(acc[mt][i][r]);
  }
  __syncthreads();

  if (t < 256) {
    int l = t >> 4, tcc = t & 15;
    size_t lrow = (size_t)b * 1024 + l0 + l;
    int px = tcc * 16 + l;

    // Q/K split bf16 (verified packing): Q = [qh][ql][qh], K = [kh][kh][kl]
    // so dot = qh*kh + ql*kh + qh*kl (drops only ~2e-4 ql*kl term).
    union { ushort s[8]; uint4 v; } qh, ql, kh, kl;
    #pragma unroll
    for (int o = 0; o < 8; ++o) {
      float qv = qkl[o * 260 + px];
      ushort h = f2bf(qv);
      qh.s[o] = h; ql.s[o] = f2bf(qv - bf2f(h));
      float kv = qkl[(8 + o) * 260 + px];
      h = f2bf(kv);
      kh.s[o] = h; kl.s[o] = f2bf(kv - bf2f(h));
    }
    ushort* qrow = Qt2 + lrow * 384 + tcc * 8;
    *(uint4*)qrow         = qh.v;
    *(uint4*)(qrow + 128) = ql.v;
    *(uint4*)(qrow + 256) = qh.v;
    ushort* krow = Kt2 + lrow * 384 + tcc * 8;
    *(uint4*)krow         = kh.v;
    *(uint4*)(krow + 128) = kh.v;
    *(uint4*)(krow + 256) = kl.v;

    // Vt row: Vt[lrow][c2*16+tt] = vl[c2][tt*16+l]
    ushort* vrow = Vt + lrow * 1024;
    #pragma unroll
    for (int it = 0; it < 4; ++it) {
      int c2 = (it << 4) + tcc;
      union { ushort s[16]; uint4 q[2]; } ov;
      #pragma unroll
      for (int tt = 0; tt < 16; ++tt)
        ov.s[tt] = vl[c2 * 264 + tt * 16 + l];
      *(uint4*)(vrow + c2 * 16)     = ov.q[0];
      *(uint4*)(vrow + c2 * 16 + 8) = ov.q[1];
    }
  }
}

// ---------------- Kernels 2/4: 256x256-tile NT bf16 MFMA GEMM (R15) ----------
template<int KTOT, bool ADDX>
__global__ __launch_bounds__(512, 2) void gemm256(
    const ushort* __restrict__ A, int lda,
    const ushort* __restrict__ B, int ldb,
    float* __restrict__ C, const float* __restrict__ X)
{
  __shared__ ushort AB[2][2][16384];   // [buf][A/B][256*64]
  int t = threadIdx.x;

  // bijective XCD-chunk remap: 256 blocks, 32 per XCD = 2 batches
  int g = blockIdx.x;
  int lin = (g & 7) * 32 + (g >> 3);
  int bz = lin >> 4;
  int by = (lin >> 2) & 3;
  int bx = lin & 3;
  int m0 = by << 8, n0 = bx << 8;

  const ushort* Ab = A + (size_t)bz * 1024 * lda;
  const ushort* Bb = B + (size_t)bz * 1024 * ldb;
  int w = t >> 6, lane = t & 63;
  int wm = w >> 2, wn = w & 3;
  int l15 = lane & 15, l4 = lane >> 4;

  int swc = (t & 7) ^ ((t >> 3) & 7);
  const ushort* pa = Ab + (size_t)(m0 + (t >> 3)) * lda + swc * 8;
  const ushort* pb = Bb + (size_t)(n0 + (t >> 3)) * ldb + swc * 8;
  int wb = w * 512;   // wave base within an 8KB staging round (elems)

  f32x4 acc[8][4] = {};
  constexpr int NT = KTOT / 64;

  // prologue: stage tile 0 into buffer 0
  #pragma unroll
  for (int i = 0; i < 4; ++i)
    gload16(pa + (size_t)i * 64 * lda, AB[0][0] + i * 4096 + wb);
  #pragma unroll
  for (int i = 0; i < 4; ++i)
    gload16(pb + (size_t)i * 64 * ldb, AB[0][1] + i * 4096 + wb);
  asm volatile("s_waitcnt vmcnt(0)" ::: "memory");
  __builtin_amdgcn_s_barrier();

  for (int it = 0; it < NT; ++it) {
    int cur = it & 1;
    const ushort* As = AB[cur][0];
    const ushort* Bs = AB[cur][1];
    if (it + 1 < NT) {              // prefetch next tile (hides under compute)
      int k0 = (it + 1) * 64;
      ushort* An = AB[cur ^ 1][0];
      ushort* Bn = AB[cur ^ 1][1];
      #pragma unroll
      for (int i = 0; i < 4; ++i)
        gload16(pa + (size_t)i * 64 * lda + k0, An + i * 4096 + wb);
      #pragma unroll
      for (int i = 0; i < 4; ++i)
        gload16(pb + (size_t)i * 64 * ldb + k0, Bn + i * 4096 + wb);
    }
    #pragma unroll
    for (int kk = 0; kk < 2; ++kk) {
      short8 af[8], bfr[4];
      #pragma unroll
      for (int mi = 0; mi < 8; ++mi) {
        int rr = (wm << 7) + (mi << 4) + l15;
        af[mi] = __builtin_bit_cast(short8,
            ((const uint4*)As)[rr * 8 + ((kk * 4 + l4) ^ (rr & 7))]);
      }
      #pragma unroll
      for (int ni = 0; ni < 4; ++ni) {
        int rr = (wn << 6) + (ni << 4) + l15;
        bfr[ni] = __builtin_bit_cast(short8,
            ((const uint4*)Bs)[rr * 8 + ((kk * 4 + l4) ^ (rr & 7))]);
      }
      #pragma unroll
      for (int mi = 0; mi < 8; ++mi)
        #pragma unroll
        for (int ni = 0; ni < 4; ++ni)
          acc[mi][ni] = __builtin_amdgcn_mfma_f32_16x16x32_bf16(
              af[mi], bfr[ni], acc[mi][ni], 0, 0, 0);
    }
    asm volatile("s_waitcnt vmcnt(0)" ::: "memory");  // next buffer staged
    __builtin_amdgcn_s_barrier();   // all waves done reading buf[cur]
  }

  #pragma unroll
  for (int mi = 0; mi < 8; ++mi) {
    int rbase = m0 + (wm << 7) + (mi << 4) + (l4 << 2);
    #pragma unroll
    for (int ni = 0; ni < 4; ++ni) {
      int col = n0 + (wn << 6) + (ni << 4) + l15;
      f32x4 v = acc[mi][ni];
      #pragma unroll
      for (int rr = 0; rr < 4; ++rr) {
        size_t idx = ((size_t)bz * 1024 + rbase + rr) * 1024 + col;
        if (ADDX) C[idx] = v[rr] + X[idx];
        else      C[idx] = v[rr];
      }
    }
  }
}

// ---------------- Kernel 3: row softmax, P bf16 in place ---------------------
__global__ __launch_bounds__(256) void softmax_rows(float* __restrict__ S)
{
  size_t rowi = blockIdx.x;
  float* srow = S + rowi * 1024;
  int t = threadIdx.x;
  float4 v = ((const float4*)srow)[t];
  float m = fmaxf(fmaxf(v.x, v.y), fmaxf(v.z, v.w));
  #pragma unroll
  for (int off = 32; off > 0; off >>= 1) m = fmaxf(m, __shfl_xor(m, off));
  __shared__ float red[8];
  int wid = t >> 6, lane = t & 63;
  if (lane == 0) red[wid] = m;
  __syncthreads();
  m = fmaxf(fmaxf(red[0], red[1]), fmaxf(red[2], red[3]));
  float e0 = __expf(v.x - m), e1 = __expf(v.y - m);
  float e2 = __expf(v.z - m), e3 = __expf(v.w - m);
  float s = e0 + e1 + e2 + e3;
  #pragma unroll
  for (int off = 32; off > 0; off >>= 1) s += __shfl_xor(s, off);
  if (lane == 0) red[4 + wid] = s;
  __syncthreads();
  s = red[4] + red[5] + red[6] + red[7];
  float inv = 1.0f / s;
  union { ushort h[4]; uint2 q; } pk;
  pk.h[0] = f2bf(e0 * inv); pk.h[1] = f2bf(e1 * inv);
  pk.h[2] = f2bf(e2 * inv); pk.h[3] = f2bf(e3 * inv);
  ((uint2*)srow)[t] = pk.q;
}

// ---------------- Launch -----------------------------------------------------
extern "C" void kernel_launch(void* const* d_in, const int* in_sizes, int n_in,
                              void* d_out, int out_size, void* d_ws, size_t ws_size,
                              hipStream_t stream) {
  const float* x  = (const float*)d_in[0];
  const float* Wq = (const float*)d_in[1];
  const float* bq = (const float*)d_in[2];
  const float* Wk = (const float*)d_in[3];
  const float* bk = (const float*)d_in[4];
  const float* Wv = (const float*)d_in[5];
  const float* bv = (const float*)d_in[6];
  float* out = (float*)d_out;

  char* wsb = (char*)d_ws;
  ushort* Qt2 = (ushort*)wsb;                          // 12,582,912 B
  ushort* Kt2 = (ushort*)(wsb + 12582912);             // 12,582,912 B
  ushort* Vt  = (ushort*)(wsb + 25165824);             // 33,554,432 B
  float*  S   = (float*)(wsb + 58720256);              // 67,108,864 B (P in place)
  ushort* Wpk = (ushort*)(wsb + 92274688);             // inside S, dead before gemm1
  float*  bpk = (float*)(wsb + 92274688 + 24576);

  prep_w2<<<49, 256, 0, stream>>>(Wq, bq, Wk, bk, Wv, bv, Wpk, bpk);
  proj11<<<1024, 512, 0, stream>>>(x, Wpk, bpk, Qt2, Kt2, Vt);
  gemm256<384, false><<<256, 512, 0, stream>>>(Qt2, 384, Kt2, 384, S, nullptr);
  softmax_rows<<<16384, 256, 0, stream>>>(S);
  gemm256<1024, true><<<256, 512, 0, stream>>>((const ushort*)S, 2048, Vt, 1024, out, x);
}

// Round 17
// 126.457 us; speedup vs baseline: 1.0615x; 1.0615x over previous
//
#include <hip/hip_runtime.h>
#include <stdint.h>

typedef uint32_t u32;
typedef __attribute__((ext_vector_type(4))) float f32x4;
typedef __attribute__((ext_vector_type(8))) short short8;

#define NBATCH 16
#define NPIX   16384      // H*W
#define NPB    1048576    // per-batch flat elems (C*H*W = 1024*1024)

__device__ __forceinline__ ushort f2bf(float f) {
  u32 b = __builtin_bit_cast(u32, f);
  return (ushort)((b + 0x7FFFu + ((b >> 16) & 1u)) >> 16);
}
__device__ __forceinline__ float bf2f(ushort h) {
  return __builtin_bit_cast(float, (u32)h << 16);
}

// async global->LDS, 16B per lane. LDS dest must be wave-uniform base;
// HW scatters lane i at base + i*16. Global source is per-lane.
__device__ __forceinline__ void gload16(const void* g, void* l) {
  __builtin_amdgcn_global_load_lds(
      (const __attribute__((address_space(1))) u32*)g,
      (__attribute__((address_space(3))) u32*)l,
      16, 0, 0);
}

// ---------------- Kernel 0: pack weights for MFMA-proj -----------------------
// Wpk[96][128] bf16: rows 0..15 = q,k: cols[0:64]=Wh (round), [64:128]=Wl
// (W - Wh, exact split). Rows 16..79 = v: cols[0:64]=bf16(Wv), rest 0.
__global__ void prep_w2(const float* __restrict__ Wq, const float* __restrict__ bq,
                        const float* __restrict__ Wk, const float* __restrict__ bk,
                        const float* __restrict__ Wv, const float* __restrict__ bv,
                        ushort* __restrict__ Wpk, float* __restrict__ bpk)
{
  int gid = blockIdx.x * 256 + threadIdx.x;
  if (gid < 12288) {
    int m = gid >> 7, kk = gid & 127;
    int ch = kk & 63;
    ushort outv = 0;
    if (m < 8) {
      float wv = Wq[m * 64 + ch];
      ushort h = f2bf(wv);
      outv = (kk < 64) ? h : f2bf(wv - bf2f(h));
    } else if (m < 16) {
      float wv = Wk[(m - 8) * 64 + ch];
      ushort h = f2bf(wv);
      outv = (kk < 64) ? h : f2bf(wv - bf2f(h));
    } else if (m < 80) {
      outv = (kk < 64) ? f2bf(Wv[(m - 16) * 64 + ch]) : (ushort)0;
    }
    Wpk[gid] = outv;
  } else if (gid < 12368) {
    int o = gid - 12288;
    bpk[o] = (o < 8) ? bq[o] : (o < 16 ? bk[o - 8] : bv[o - 16]);
  }
}

// ---------------- Kernel 1: MFMA proj + fused transposes (R15-verified) ------
__global__ __launch_bounds__(256) void proj10(
    const float* __restrict__ x, const ushort* __restrict__ Wpk,
    const float* __restrict__ bpk,
    ushort* __restrict__ Qt2, ushort* __restrict__ Kt2,
    ushort* __restrict__ Vt)
{
  __shared__ __align__(16) char smem[32768];
  float* xs = (float*)smem;                       // [64][128]
  int t = threadIdx.x;
  int w = t >> 6, lane = t & 63;
  int l15 = lane & 15, l4 = lane >> 4;

  int g = blockIdx.x;
  int lin = (g & 7) * 256 + (g >> 3);
  int b = lin >> 7;
  int l0 = (lin & 127) << 3;
  const float* xb = x + (size_t)b * NPB + l0;

  #pragma unroll
  for (int it = 0; it < 8; ++it) {
    int f0 = (it * 4 + w) * 64;
    int f = f0 + lane;
    int ch = f >> 5, r2 = f & 31, tc = r2 >> 1, half = r2 & 1;
    gload16(xb + (size_t)ch * NPIX + tc * 1024 + half * 4, xs + f0 * 4);
  }

  const uint4* Wp4 = (const uint4*)Wpk;   // row stride 16 uint4
  uint4 Afrag[12];
  #pragma unroll
  for (int kc = 0; kc < 4; ++kc)
    Afrag[kc] = Wp4[l15 * 16 + kc * 4 + l4];
  #pragma unroll
  for (int mt = 1; mt < 5; ++mt)
    #pragma unroll
    for (int kc = 0; kc < 2; ++kc)
      Afrag[2 + mt * 2 + kc] = Wp4[(mt * 16 + l15) * 16 + kc * 4 + l4];

  f32x4 acc[5][2];
  #pragma unroll
  for (int mt = 0; mt < 5; ++mt) {
    f32x4 bv4;
    #pragma unroll
    for (int r = 0; r < 4; ++r) bv4[r] = bpk[mt * 16 + l4 * 4 + r];
    acc[mt][0] = bv4; acc[mt][1] = bv4;
  }

  __syncthreads();

  #pragma unroll
  for (int i = 0; i < 2; ++i) {
    int px = (w * 2 + i) * 16 + l15;
    u32 xr[16];
    #pragma unroll
    for (int kc = 0; kc < 2; ++kc)
      #pragma unroll
      for (int j = 0; j < 8; ++j)
        xr[kc * 8 + j] = ((const u32*)xs)[(kc * 32 + l4 * 8 + j) * 128 + px];
    uint4 bxh[2], bxl[2];
    #pragma unroll
    for (int kc = 0; kc < 2; ++kc)
      #pragma unroll
      for (int p = 0; p < 4; ++p) {
        u32 a = xr[kc * 8 + 2 * p], c = xr[kc * 8 + 2 * p + 1];
        ((u32*)&bxh[kc])[p] = (a >> 16) | (c & 0xFFFF0000u);
        float fa = __builtin_bit_cast(float, a) -
                   __builtin_bit_cast(float, a & 0xFFFF0000u);
        float fc = __builtin_bit_cast(float, c) -
                   __builtin_bit_cast(float, c & 0xFFFF0000u);
        u32 la = __builtin_bit_cast(u32, fa), lc = __builtin_bit_cast(u32, fc);
        ((u32*)&bxl[kc])[p] = (la >> 16) | (lc & 0xFFFF0000u);
      }
    short8 h0 = __builtin_bit_cast(short8, bxh[0]);
    short8 h1 = __builtin_bit_cast(short8, bxh[1]);
    short8 s0 = __builtin_bit_cast(short8, bxl[0]);
    short8 s1 = __builtin_bit_cast(short8, bxl[1]);
    acc[0][i] = __builtin_amdgcn_mfma_f32_16x16x32_bf16(
        __builtin_bit_cast(short8, Afrag[0]), h0, acc[0][i], 0, 0, 0);
    acc[0][i] = __builtin_amdgcn_mfma_f32_16x16x32_bf16(
        __builtin_bit_cast(short8, Afrag[1]), h1, acc[0][i], 0, 0, 0);
    acc[0][i] = __builtin_amdgcn_mfma_f32_16x16x32_bf16(
        __builtin_bit_cast(short8, Afrag[0]), s0, acc[0][i], 0, 0, 0);
    acc[0][i] = __builtin_amdgcn_mfma_f32_16x16x32_bf16(
        __builtin_bit_cast(short8, Afrag[1]), s1, acc[0][i], 0, 0, 0);
    acc[0][i] = __builtin_amdgcn_mfma_f32_16x16x32_bf16(
        __builtin_bit_cast(short8, Afrag[2]), h0, acc[0][i], 0, 0, 0);
    acc[0][i] = __builtin_amdgcn_mfma_f32_16x16x32_bf16(
        __builtin_bit_cast(short8, Afrag[3]), h1, acc[0][i], 0, 0, 0);
    #pragma unroll
    for (int mt = 1; mt < 5; ++mt) {
      acc[mt][i] = __builtin_amdgcn_mfma_f32_16x16x32_bf16(
          __builtin_bit_cast(short8, Afrag[2 + mt * 2]), h0, acc[mt][i], 0, 0, 0);
      acc[mt][i] = __builtin_amdgcn_mfma_f32_16x16x32_bf16(
          __builtin_bit_cast(short8, Afrag[3 + mt * 2]), h1, acc[mt][i], 0, 0, 0);
    }
  }
  __syncthreads();

  float*  qkl = (float*)smem;                    // [16][132]
  ushort* vl  = (ushort*)(smem + 16 * 132 * 4);  // [64][136]
  #pragma unroll
  for (int i = 0; i < 2; ++i) {
    int px = (w * 2 + i) * 16 + l15;
    #pragma unroll
    for (int r = 0; r < 4; ++r)
      qkl[(l4 * 4 + r) * 132 + px] = acc[0][i][r];
    #pragma unroll
    for (int mt = 1; mt < 5; ++mt)
      #pragma unroll
      for (int r = 0; r < 4; ++r)
        vl[((mt - 1) * 16 + l4 * 4 + r) * 136 + px] = f2bf(acc[mt][i][r]);
  }
  __syncthreads();

  if (t < 128) {
    int l = t >> 4, tcc = t & 15;
    size_t lrow = (size_t)b * 1024 + l0 + l;
    int px = tcc * 8 + l;

    union { ushort s[8]; uint4 v; } qh, ql, kh, kl;
    #pragma unroll
    for (int o = 0; o < 8; ++o) {
      float qv = qkl[o * 132 + px];
      ushort h = f2bf(qv);
      qh.s[o] = h; ql.s[o] = f2bf(qv - bf2f(h));
      float kv = qkl[(8 + o) * 132 + px];
      h = f2bf(kv);
      kh.s[o] = h; kl.s[o] = f2bf(kv - bf2f(h));
    }
    ushort* qrow = Qt2 + lrow * 384 + tcc * 8;
    *(uint4*)qrow         = qh.v;
    *(uint4*)(qrow + 128) = ql.v;
    *(uint4*)(qrow + 256) = qh.v;
    ushort* krow = Kt2 + lrow * 384 + tcc * 8;
    *(uint4*)krow         = kh.v;
    *(uint4*)(krow + 128) = kh.v;
    *(uint4*)(krow + 256) = kl.v;

    ushort* vrow = Vt + lrow * 1024;
    #pragma unroll
    for (int it = 0; it < 4; ++it) {
      int c2 = (it << 4) + tcc;
      union { ushort s[16]; uint4 q[2]; } ov;
      #pragma unroll
      for (int tt = 0; tt < 16; ++tt)
        ov.s[tt] = vl[c2 * 136 + tt * 8 + l];
      *(uint4*)(vrow + c2 * 16)     = ov.q[0];
      *(uint4*)(vrow + c2 * 16 + 8) = ov.q[1];
    }
  }
}

// ---------------- Kernels 2/4: 256x256 NT bf16 MFMA GEMM, counted vmcnt ------
// C[i][j] = sum_k A[i][k]*B[j][k]; per-batch 1024x1024. BM=BN=256, BK=64,
// 8 waves (2Mx4N), double-buffered 128KB LDS. T4 counted-vmcnt pipeline:
// prologue stages tiles 0 AND 1; per iter: vmcnt(8) [own 8 loads of tile t
// landed; t+1's 8 may stay in flight across the barrier], barrier, compute,
// barrier, stage tile t+2 into the buffer just consumed. Never drains to 0
// in the main loop -> the per-iter exposed load latency of the R15 drain-0
// structure is removed. Race-safety: barrier2 precedes re-staging of the
// consumed buffer; staging is wave-symmetric (8 gload16/tile/wave) so
// per-wave vmcnt semantics imply block-wide completion after the barrier.
// Verified src-side XOR swizzle + fragment/C-write maps unchanged.
template<int KTOT, bool ADDX>
__global__ __launch_bounds__(512, 2) void gemm256(
    const ushort* __restrict__ A, int lda,
    const ushort* __restrict__ B, int ldb,
    float* __restrict__ C, const float* __restrict__ X)
{
  __shared__ ushort AB[2][2][16384];   // [buf][A/B][256*64]
  int t = threadIdx.x;

  // bijective XCD-chunk remap: 256 blocks, 32 per XCD = 2 batches
  int g = blockIdx.x;
  int lin = (g & 7) * 32 + (g >> 3);
  int bz = lin >> 4;
  int by = (lin >> 2) & 3;
  int bx = lin & 3;
  int m0 = by << 8, n0 = bx << 8;

  const ushort* Ab = A + (size_t)bz * 1024 * lda;
  const ushort* Bb = B + (size_t)bz * 1024 * ldb;
  int w = t >> 6, lane = t & 63;
  int wm = w >> 2, wn = w & 3;
  int l15 = lane & 15, l4 = lane >> 4;

  int swc = (t & 7) ^ ((t >> 3) & 7);
  const ushort* pa = Ab + (size_t)(m0 + (t >> 3)) * lda + swc * 8;
  const ushort* pb = Bb + (size_t)(n0 + (t >> 3)) * ldb + swc * 8;
  int wb = w * 512;   // wave base within an 8KB staging round (elems)

  f32x4 acc[8][4] = {};
  constexpr int NT = KTOT / 64;

  // prologue: stage tiles 0 and 1 (16 loads/wave in flight, no drain)
  #pragma unroll
  for (int i = 0; i < 4; ++i)
    gload16(pa + (size_t)i * 64 * lda, AB[0][0] + i * 4096 + wb);
  #pragma unroll
  for (int i = 0; i < 4; ++i)
    gload16(pb + (size_t)i * 64 * ldb, AB[0][1] + i * 4096 + wb);
  #pragma unroll
  for (int i = 0; i < 4; ++i)
    gload16(pa + (size_t)i * 64 * lda + 64, AB[1][0] + i * 4096 + wb);
  #pragma unroll
  for (int i = 0; i < 4; ++i)
    gload16(pb + (size_t)i * 64 * ldb + 64, AB[1][1] + i * 4096 + wb);

  for (int it = 0; it < NT; ++it) {
    int cur = it & 1;
    // tile `it`'s 8 own loads landed; tile it+1's 8 may remain in flight
    asm volatile("s_waitcnt vmcnt(8)" ::: "memory");
    __builtin_amdgcn_sched_barrier(0);
    __builtin_amdgcn_s_barrier();

    const ushort* As = AB[cur][0];
    const ushort* Bs = AB[cur][1];
    #pragma unroll
    for (int kk = 0; kk < 2; ++kk) {
      short8 af[8], bfr[4];
      #pragma unroll
      for (int mi = 0; mi < 8; ++mi) {
        int rr = (wm << 7) + (mi << 4) + l15;
        af[mi] = __builtin_bit_cast(short8,
            ((const uint4*)As)[rr * 8 + ((kk * 4 + l4) ^ (rr & 7))]);
      }
      #pragma unroll
      for (int ni = 0; ni < 4; ++ni) {
        int rr = (wn << 6) + (ni << 4) + l15;
        bfr[ni] = __builtin_bit_cast(short8,
            ((const uint4*)Bs)[rr * 8 + ((kk * 4 + l4) ^ (rr & 7))]);
      }
      #pragma unroll
      for (int mi = 0; mi < 8; ++mi)
        #pragma unroll
        for (int ni = 0; ni < 4; ++ni)
          acc[mi][ni] = __builtin_amdgcn_mfma_f32_16x16x32_bf16(
              af[mi], bfr[ni], acc[mi][ni], 0, 0, 0);
    }

    asm volatile("" ::: "memory");
    __builtin_amdgcn_s_barrier();     // all waves done reading AB[cur]
    __builtin_amdgcn_sched_barrier(0);
    if (it + 2 < NT) {                // re-stage the consumed buffer
      int k0 = (it + 2) * 64;
      ushort* An = AB[cur][0];
      ushort* Bn = AB[cur][1];
      #pragma unroll
      for (int i = 0; i < 4; ++i)
        gload16(pa + (size_t)i * 64 * lda + k0, An + i * 4096 + wb);
      #pragma unroll
      for (int i = 0; i < 4; ++i)
        gload16(pb + (size_t)i * 64 * ldb + k0, Bn + i * 4096 + wb);
    }
  }

  #pragma unroll
  for (int mi = 0; mi < 8; ++mi) {
    int rbase = m0 + (wm << 7) + (mi << 4) + (l4 << 2);
    #pragma unroll
    for (int ni = 0; ni < 4; ++ni) {
      int col = n0 + (wn << 6) + (ni << 4) + l15;
      f32x4 v = acc[mi][ni];
      #pragma unroll
      for (int rr = 0; rr < 4; ++rr) {
        size_t idx = ((size_t)bz * 1024 + rbase + rr) * 1024 + col;
        if (ADDX) C[idx] = v[rr] + X[idx];
        else      C[idx] = v[rr];
      }
    }
  }
}

// ---------------- Kernel 3: row softmax, P bf16 in place ---------------------
__global__ __launch_bounds__(256) void softmax_rows(float* __restrict__ S)
{
  size_t rowi = blockIdx.x;
  float* srow = S + rowi * 1024;
  int t = threadIdx.x;
  float4 v = ((const float4*)srow)[t];
  float m = fmaxf(fmaxf(v.x, v.y), fmaxf(v.z, v.w));
  #pragma unroll
  for (int off = 32; off > 0; off >>= 1) m = fmaxf(m, __shfl_xor(m, off));
  __shared__ float red[8];
  int wid = t >> 6, lane = t & 63;
  if (lane == 0) red[wid] = m;
  __syncthreads();
  m = fmaxf(fmaxf(red[0], red[1]), fmaxf(red[2], red[3]));
  float e0 = __expf(v.x - m), e1 = __expf(v.y - m);
  float e2 = __expf(v.z - m), e3 = __expf(v.w - m);
  float s = e0 + e1 + e2 + e3;
  #pragma unroll
  for (int off = 32; off > 0; off >>= 1) s += __shfl_xor(s, off);
  if (lane == 0) red[4 + wid] = s;
  __syncthreads();
  s = red[4] + red[5] + red[6] + red[7];
  float inv = 1.0f / s;
  union { ushort h[4]; uint2 q; } pk;
  pk.h[0] = f2bf(e0 * inv); pk.h[1] = f2bf(e1 * inv);
  pk.h[2] = f2bf(e2 * inv); pk.h[3] = f2bf(e3 * inv);
  ((uint2*)srow)[t] = pk.q;
}

// ---------------- Launch -----------------------------------------------------
extern "C" void kernel_launch(void* const* d_in, const int* in_sizes, int n_in,
                              void* d_out, int out_size, void* d_ws, size_t ws_size,
                              hipStream_t stream) {
  const float* x  = (const float*)d_in[0];
  const float* Wq = (const float*)d_in[1];
  const float* bq = (const float*)d_in[2];
  const float* Wk = (const float*)d_in[3];
  const float* bk = (const float*)d_in[4];
  const float* Wv = (const float*)d_in[5];
  const float* bv = (const float*)d_in[6];
  float* out = (float*)d_out;

  char* wsb = (char*)d_ws;
  ushort* Qt2 = (ushort*)wsb;                          // 12,582,912 B
  ushort* Kt2 = (ushort*)(wsb + 12582912);             // 12,582,912 B
  ushort* Vt  = (ushort*)(wsb + 25165824);             // 33,554,432 B
  float*  S   = (float*)(wsb + 58720256);              // 67,108,864 B (P in place)
  ushort* Wpk = (ushort*)(wsb + 92274688);             // inside S, dead before gemm1
  float*  bpk = (float*)(wsb + 92274688 + 24576);

  prep_w2<<<49, 256, 0, stream>>>(Wq, bq, Wk, bk, Wv, bv, Wpk, bpk);
  proj10<<<2048, 256, 0, stream>>>(x, Wpk, bpk, Qt2, Kt2, Vt);
  gemm256<384, false><<<256, 512, 0, stream>>>(Qt2, 384, Kt2, 384, S, nullptr);
  softmax_rows<<<16384, 256, 0, stream>>>(S);
  gemm256<1024, true><<<256, 512, 0, stream>>>((const ushort*)S, 2048, Vt, 1024, out, x);
}